// Round 8
// baseline (481.096 us; speedup 1.0000x reference)
//
#include <hip/hip_runtime.h>
#include <stddef.h>

#define NN 512
#define CC 128
#define NPOS (NN*NN)
#define CPITCH (NPOS + 512)

typedef unsigned short u16;
typedef unsigned int   u32;
typedef u16  u16x4  __attribute__((ext_vector_type(4)));
typedef u16  u16x8  __attribute__((ext_vector_type(8)));
typedef __bf16 bf16x8 __attribute__((ext_vector_type(8)));
typedef float f32x4  __attribute__((ext_vector_type(4)));

__device__ __forceinline__ float b2f(u16 u) {
    union { u32 i; float f; } w; w.i = ((u32)u) << 16; return w.f;
}
__device__ __forceinline__ u16 f2b(float f) {
    return __builtin_bit_cast(u16, (__bf16)f);
}
__device__ __forceinline__ float sigm(float x) { return 1.0f / (1.0f + __expf(-x)); }

__device__ __forceinline__ void gld16(const u16* g, u16* l) {
    __builtin_amdgcn_global_load_lds(
        (const __attribute__((address_space(1))) u32*)g,
        (__attribute__((address_space(3))) u32*)l, 16, 0, 0);
}

struct W6 { const float* p[6]; };   // 0:agw 1:apw 2:bgw 3:bpw 4:gw 5:zw

// ---------------------------------------------------------------------------
// K0: pack 6 [128x128] f32 weight matrices into bf16 MFMA-fragment order.
// ---------------------------------------------------------------------------
__global__ __launch_bounds__(256) void k0_pack(W6 w, u16* __restrict__ dst)
{
    const int i = blockIdx.x * 256 + threadIdx.x;     // 6*16384 total
    const int mt = i >> 14, r = i & 16383;
    const int cb = r >> 11, ks = (r >> 9) & 3, lane = (r >> 3) & 63, j = r & 7;
    const int row = cb * 16 + (lane & 15);
    const int col = ks * 32 + (lane >> 4) * 8 + j;
    dst[i] = f2b(w.p[mt][row * 128 + col]);
}

// ---------------------------------------------------------------------------
// K1 (wave-owns-cb, weights-stationary, high-occupancy):
// 512 threads / 128 positions per block. Wave w owns output block cb=w:
// its 16 weight fragments (4 matrices x 4 ks) are loaded ONCE into 64 VGPR;
// the 8-tile main loop has NO global loads (ds_read + MFMA + stores only).
// Unlike the R5 attempt, VGPR stays ~112 (4 waves/SIMD) and LDS 35 KB
// (2 blocks/CU) -> ~50% occupancy, so the test is not confounded.
// ---------------------------------------------------------------------------
__global__ __launch_bounds__(512) void k1_ln_proj(
    const float* __restrict__ z,  const float* __restrict__ mask,
    const float* __restrict__ wi, const float* __restrict__ bi,
    const u16* __restrict__ wpk,
    const float* __restrict__ agb, const float* __restrict__ apb,
    const float* __restrict__ bgb, const float* __restrict__ bpb,
    u16* __restrict__ a_cm, u16* __restrict__ b_cm,
    u16* __restrict__ zn_pm)
{
    __shared__ u16   zn[128][136];   // bf16 normalized z, pitch 136 (34.8 KB)
    __shared__ float mk_lds[128];
    const int tid = threadIdx.x;
    const size_t p0 = (size_t)blockIdx.x * 128;

    if (tid < 128) mk_lds[tid] = mask[p0 + tid];

    {   // ---- LayerNorm: 16 groups of 32 lanes; group g owns rows h*16+g ----
        const int g  = tid >> 5;            // 0..15
        const int c4 = (tid & 31) * 4;      // channel base
        const f32x4 wi4 = *(const f32x4*)(wi + c4);
        const f32x4 bi4 = *(const f32x4*)(bi + c4);
        f32x4 v[8];
        #pragma unroll
        for (int h = 0; h < 8; ++h)
            v[h] = *(const f32x4*)(z + (p0 + h * 16 + g) * CC + c4);
        #pragma unroll
        for (int h = 0; h < 8; ++h) {
            float s  = (v[h][0] + v[h][1]) + (v[h][2] + v[h][3]);
            float s2 = (v[h][0]*v[h][0] + v[h][1]*v[h][1])
                     + (v[h][2]*v[h][2] + v[h][3]*v[h][3]);
            #pragma unroll
            for (int ms = 1; ms <= 16; ms <<= 1) {
                s  += __shfl_xor(s,  ms);
                s2 += __shfl_xor(s2, ms);
            }
            const float mu   = s * (1.0f / CC);
            const float rstd = rsqrtf(s2 * (1.0f / CC) - mu * mu + 1e-5f);
            u16x4 o4;
            #pragma unroll
            for (int e = 0; e < 4; ++e) {
                const float nw = rstd * wi4[e];
                o4[e] = f2b(v[h][e] * nw + __builtin_fmaf(-mu, nw, bi4[e]));
            }
            const int row = h * 16 + g;
            *(u16x4*)&zn[row][c4] = o4;
            if (zn_pm)
                *(u16x4*)(zn_pm + (p0 + row) * CC + c4) = o4;
        }
    }

    // ---- weight prologue: this wave's cb, loaded once into registers ----
    const int wave = tid >> 6, lane = tid & 63;
    const int m = lane & 15, q = lane >> 4;
    const int cb = wave;                 // wave owns one 16-channel block
    const int o  = cb * 16 + m;

    bf16x8 wreg[4][4];                   // [matrix][ks] = 64 VGPR
    float  bias4[4];
    {
        const float* Bv[4] = { agb, apb, bgb, bpb };
        #pragma unroll
        for (int mt = 0; mt < 4; ++mt) {
            bias4[mt] = Bv[mt][o];
            const u16* wp = wpk + ((size_t)((mt * 8 + cb) * 4)) * 512
                                + (size_t)lane * 8;
            #pragma unroll
            for (int ks = 0; ks < 4; ++ks)
                wreg[mt][ks] = *(const bf16x8*)(wp + ks * 512);
        }
    }
    __syncthreads();

    // ---- 8 position-tiles; no global loads in this loop ----
    #pragma unroll 2
    for (int t = 0; t < 8; ++t) {
        bf16x8 af[4];
        #pragma unroll
        for (int ks = 0; ks < 4; ++ks)
            af[ks] = *(const bf16x8*)&zn[t * 16 + m][ks * 32 + q * 8];
        const f32x4 mk4 = *(const f32x4*)&mk_lds[t * 16 + q * 4];

        f32x4 res[4];
        #pragma unroll
        for (int mt = 0; mt < 4; ++mt) {
            const float bv = bias4[mt];
            res[mt] = f32x4{ bv, bv, bv, bv };
        }
        #pragma unroll
        for (int ks = 0; ks < 4; ++ks)
            #pragma unroll
            for (int mt = 0; mt < 4; ++mt)
                res[mt] = __builtin_amdgcn_mfma_f32_16x16x32_bf16(
                            af[ks], wreg[mt][ks], res[mt], 0, 0, 0);

        u16x4 av, bv;
        #pragma unroll
        for (int r = 0; r < 4; ++r) {
            const float mk = mk4[r];
            av[r] = f2b(mk * sigm(res[0][r]) * res[1][r]);
            bv[r] = f2b(mk * sigm(res[2][r]) * res[3][r]);
        }
        const size_t off = (size_t)o * CPITCH + p0 + t * 16 + q * 4;
        *(u16x4*)(a_cm + off) = av;
        *(u16x4*)(b_cm + off) = bv;
    }
}

// ---------------------------------------------------------------------------
// K2: per-channel 512x512x512 NT GEMM, XCD-affine, K=32 ping-pong
// double-buffer (issue next tile's loads -> compute current -> barrier).
// Unchanged from R7 (measured win).
// ---------------------------------------------------------------------------
__global__ __launch_bounds__(256) void k2_gemm(
    const u16* __restrict__ A, const u16* __restrict__ B, u16* __restrict__ X)
{
    __shared__ u16 As[2][128][32];
    __shared__ u16 Bs[2][128][32];
    const int tid = threadIdx.x;
    const int bx  = blockIdx.x;
    const int xcd  = bx & 7;
    const int slot = bx >> 3;              // 0..255 per XCD
    const int c    = (slot >> 4) * 8 + xcd;
    const int tile = slot & 15;
    const int i0   = (tile >> 2) * 128;
    const int j0   = (tile & 3) * 128;
    const size_t cbase = (size_t)c * CPITCH;
    const u16* Ac = A + cbase;
    const u16* Bc = B + cbase;

    const int wave = tid >> 6, lane = tid & 63;
    const int wm = wave >> 1, wn = wave & 1;
    const int m = lane & 15, q = lane >> 4;

    f32x4 acc[4][4];
    const f32x4 zero = { 0.f, 0.f, 0.f, 0.f };
    #pragma unroll
    for (int mt = 0; mt < 4; ++mt)
        #pragma unroll
        for (int nt = 0; nt < 4; ++nt) acc[mt][nt] = zero;

    #pragma unroll
    for (int ps = 0; ps < 2; ++ps) {
        const int id = ps * 256 + tid;
        const int rw = id >> 2;
        const int g  = (id & 3) ^ ((rw >> 1) & 3);
        gld16(Ac + (size_t)(i0 + rw) * NN + g * 8, &As[0][0][0] + id * 8);
        gld16(Bc + (size_t)(j0 + rw) * NN + g * 8, &Bs[0][0][0] + id * 8);
    }
    __syncthreads();

    int cur = 0;
    for (int kt = 0; kt < 16; ++kt) {
        if (kt < 15) {
            const int nb = cur ^ 1;
            #pragma unroll
            for (int ps = 0; ps < 2; ++ps) {
                const int id = ps * 256 + tid;
                const int rw = id >> 2;
                const int g  = (id & 3) ^ ((rw >> 1) & 3);
                const size_t goff = (size_t)((kt + 1) * 32 + g * 8);
                gld16(Ac + (size_t)(i0 + rw) * NN + goff, &As[nb][0][0] + id * 8);
                gld16(Bc + (size_t)(j0 + rw) * NN + goff, &Bs[nb][0][0] + id * 8);
            }
        }
        bf16x8 af[4], bf[4];
        #pragma unroll
        for (int mt = 0; mt < 4; ++mt) {
            const int row = wm * 64 + mt * 16 + m;
            const int slt = q ^ ((row >> 1) & 3);
            af[mt] = *(const bf16x8*)&As[cur][row][slt * 8];
        }
        #pragma unroll
        for (int nt = 0; nt < 4; ++nt) {
            const int row = wn * 64 + nt * 16 + m;
            const int slt = q ^ ((row >> 1) & 3);
            bf[nt] = *(const bf16x8*)&Bs[cur][row][slt * 8];
        }
        #pragma unroll
        for (int mt = 0; mt < 4; ++mt)
            #pragma unroll
            for (int nt = 0; nt < 4; ++nt)
                acc[mt][nt] = __builtin_amdgcn_mfma_f32_16x16x32_bf16(
                                af[mt], bf[nt], acc[mt][nt], 0, 0, 0);
        __syncthreads();
        cur ^= 1;
    }

    #pragma unroll
    for (int mt = 0; mt < 4; ++mt) {
        #pragma unroll
        for (int r = 0; r < 4; ++r) {
            const int i = i0 + wm * 64 + mt * 16 + q * 4 + r;
            #pragma unroll
            for (int nt = 0; nt < 4; ++nt) {
                const int j = j0 + wn * 64 + nt * 16 + m;
                X[cbase + (size_t)i * NN + j] = f2b(acc[mt][nt][r]);
            }
        }
    }
}

// ---------------------------------------------------------------------------
// K3: out = (LN(x)@z_w^T + z_b) * sigmoid(zn@g_w^T + g_b), zn from handoff.
// r4 version (best measured). Unchanged.
// ---------------------------------------------------------------------------
__global__ __launch_bounds__(256) void k3_out_zn(
    float* __restrict__ out, const u16* __restrict__ x_cm,
    const u16* __restrict__ zn_pm,
    const float* __restrict__ wo, const float* __restrict__ bo,
    const u16* __restrict__ wpk,
    const float* __restrict__ gbv, const float* __restrict__ zbv)
{
    __shared__ u16 A[128][136];    // xn
    __shared__ u16 Bt[128][136];   // x tile, channel-major [c][p]
    const int tid = threadIdx.x;
    const size_t p0 = (size_t)blockIdx.x * 128;
    const int wave = tid >> 6, lane = tid & 63;
    const int m = lane & 15, q = lane >> 4;
    const int pl = tid >> 1, ht = tid & 1;

    {
        const int c = tid >> 1, seg = tid & 1;
        #pragma unroll
        for (int e = 0; e < 8; ++e) {
            u16x8 vv = *(const u16x8*)(x_cm + (size_t)c * CPITCH + p0 + seg * 64 + e * 8);
            *(u16x8*)&Bt[c][seg * 64 + e * 8] = vv;
        }
    }
    bf16x8 afz[2][4];
    #pragma unroll
    for (int t = 0; t < 2; ++t)
        #pragma unroll
        for (int ks = 0; ks < 4; ++ks)
            afz[t][ks] = *(const bf16x8*)(zn_pm
                           + (p0 + wave * 32 + t * 16 + m) * CC + ks * 32 + q * 8);
    __syncthreads();

    {
        float v[64];
        #pragma unroll
        for (int e = 0; e < 64; ++e) v[e] = b2f(Bt[ht * 64 + e][pl]);
        float s = 0.f, s2 = 0.f;
        #pragma unroll
        for (int e = 0; e < 64; ++e) { s += v[e]; s2 += v[e] * v[e]; }
        s  += __shfl_xor(s, 1);
        s2 += __shfl_xor(s2, 1);
        const float mu   = s * (1.0f / CC);
        const float rstd = rsqrtf(s2 * (1.0f / CC) - mu * mu + 1e-5f);
        #pragma unroll
        for (int h = 0; h < 8; ++h) {
            u16x8 o8;
            #pragma unroll
            for (int e = 0; e < 8; ++e) {
                const int c = ht * 64 + h * 8 + e;
                o8[e] = f2b((v[h * 8 + e] - mu) * rstd * wo[c] + bo[c]);
            }
            *(u16x8*)&A[pl][ht * 64 + h * 8] = o8;
        }
    }
    __syncthreads();

    bf16x8 afx[2][4];
    #pragma unroll
    for (int t = 0; t < 2; ++t)
        #pragma unroll
        for (int ks = 0; ks < 4; ++ks)
            afx[t][ks] = *(const bf16x8*)&A[wave * 32 + t * 16 + m][ks * 32 + q * 8];

    for (int cb = 0; cb < 8; ++cb) {
        const int o = cb * 16 + m;
        const float gb0 = gbv[o], zb0 = zbv[o];
        f32x4 accg[2], accx[2];
        #pragma unroll
        for (int t = 0; t < 2; ++t) {
            accg[t] = f32x4{ gb0, gb0, gb0, gb0 };
            accx[t] = f32x4{ zb0, zb0, zb0, zb0 };
        }
        const u16* wpg = wpk + ((size_t)((4 * 8 + cb) * 4)) * 512 + (size_t)lane * 8;
        const u16* wpz = wpk + ((size_t)((5 * 8 + cb) * 4)) * 512 + (size_t)lane * 8;
        bf16x8 wg[4], wz[4];
        #pragma unroll
        for (int ks = 0; ks < 4; ++ks) {
            wg[ks] = *(const bf16x8*)(wpg + ks * 512);
            wz[ks] = *(const bf16x8*)(wpz + ks * 512);
        }
        #pragma unroll
        for (int ks = 0; ks < 4; ++ks)
            #pragma unroll
            for (int t = 0; t < 2; ++t) {
                accg[t] = __builtin_amdgcn_mfma_f32_16x16x32_bf16(
                            afz[t][ks], wg[ks], accg[t], 0, 0, 0);
                accx[t] = __builtin_amdgcn_mfma_f32_16x16x32_bf16(
                            afx[t][ks], wz[ks], accx[t], 0, 0, 0);
            }
        #pragma unroll
        for (int t = 0; t < 2; ++t)
            #pragma unroll
            for (int r = 0; r < 4; ++r) {
                const size_t p = p0 + wave * 32 + t * 16 + q * 4 + r;
                out[p * CC + o] = accx[t][r] * sigm(accg[t][r]);
            }
    }
}

// ---------------------------------------------------------------------------
// K3 (legacy fallback, used only if workspace too small for zn handoff).
// ---------------------------------------------------------------------------
__global__ __launch_bounds__(256) void k3_out(
    float* __restrict__ out, const u16* __restrict__ x_cm,
    const float* __restrict__ z,
    const float* __restrict__ wi, const float* __restrict__ bi,
    const float* __restrict__ wo, const float* __restrict__ bo,
    const u16* __restrict__ wpk,
    const float* __restrict__ gbv, const float* __restrict__ zbv)
{
    __shared__ u16 A[128][136];
    __shared__ u16 Bt[128][136];
    const int tid = threadIdx.x;
    const size_t p0 = (size_t)blockIdx.x * 128;
    const int wave = tid >> 6, lane = tid & 63;
    const int m = lane & 15, q = lane >> 4;
    const int pl = tid >> 1, ht = tid & 1;

    {
        const float* zr = z + (p0 + pl) * CC + ht * 64;
        float v[64];
        #pragma unroll
        for (int h = 0; h < 16; ++h) {
            f32x4 t = *(const f32x4*)(zr + h * 4);
            #pragma unroll
            for (int e = 0; e < 4; ++e) v[h * 4 + e] = t[e];
        }
        float s = 0.f, s2 = 0.f;
        #pragma unroll
        for (int e = 0; e < 64; ++e) { s += v[e]; s2 += v[e] * v[e]; }
        s  += __shfl_xor(s, 1);
        s2 += __shfl_xor(s2, 1);
        const float mu   = s * (1.0f / CC);
        const float rstd = rsqrtf(s2 * (1.0f / CC) - mu * mu + 1e-5f);
        #pragma unroll
        for (int h = 0; h < 8; ++h) {
            u16x8 o8;
            #pragma unroll
            for (int e = 0; e < 8; ++e) {
                const int c = ht * 64 + h * 8 + e;
                o8[e] = f2b((v[h * 8 + e] - mu) * rstd * wi[c] + bi[c]);
            }
            *(u16x8*)&A[pl][ht * 64 + h * 8] = o8;
        }
    }
    {
        const int c = tid >> 1, seg = tid & 1;
        #pragma unroll
        for (int e = 0; e < 8; ++e) {
            u16x8 vv = *(const u16x8*)(x_cm + (size_t)c * CPITCH + p0 + seg * 64 + e * 8);
            *(u16x8*)&Bt[c][seg * 64 + e * 8] = vv;
        }
    }
    __syncthreads();

    bf16x8 afz[2][4];
    #pragma unroll
    for (int t = 0; t < 2; ++t)
        #pragma unroll
        for (int ks = 0; ks < 4; ++ks)
            afz[t][ks] = *(const bf16x8*)&A[wave * 32 + t * 16 + m][ks * 32 + q * 8];
    __syncthreads();

    {
        float v[64];
        #pragma unroll
        for (int e = 0; e < 64; ++e) v[e] = b2f(Bt[ht * 64 + e][pl]);
        float s = 0.f, s2 = 0.f;
        #pragma unroll
        for (int e = 0; e < 64; ++e) { s += v[e]; s2 += v[e] * v[e]; }
        s  += __shfl_xor(s, 1);
        s2 += __shfl_xor(s2, 1);
        const float mu   = s * (1.0f / CC);
        const float rstd = rsqrtf(s2 * (1.0f / CC) - mu * mu + 1e-5f);
        #pragma unroll
        for (int h = 0; h < 8; ++h) {
            u16x8 o8;
            #pragma unroll
            for (int e = 0; e < 8; ++e) {
                const int c = ht * 64 + h * 8 + e;
                o8[e] = f2b((v[h * 8 + e] - mu) * rstd * wo[c] + bo[c]);
            }
            *(u16x8*)&A[pl][ht * 64 + h * 8] = o8;
        }
    }
    __syncthreads();

    bf16x8 afx[2][4];
    #pragma unroll
    for (int t = 0; t < 2; ++t)
        #pragma unroll
        for (int ks = 0; ks < 4; ++ks)
            afx[t][ks] = *(const bf16x8*)&A[wave * 32 + t * 16 + m][ks * 32 + q * 8];

    for (int cb = 0; cb < 8; ++cb) {
        const int o = cb * 16 + m;
        const float gb0 = gbv[o], zb0 = zbv[o];
        f32x4 accg[2], accx[2];
        #pragma unroll
        for (int t = 0; t < 2; ++t) {
            accg[t] = f32x4{ gb0, gb0, gb0, gb0 };
            accx[t] = f32x4{ zb0, zb0, zb0, zb0 };
        }
        const u16* wpg = wpk + ((size_t)((4 * 8 + cb) * 4)) * 512 + (size_t)lane * 8;
        const u16* wpz = wpk + ((size_t)((5 * 8 + cb) * 4)) * 512 + (size_t)lane * 8;
        bf16x8 wg[4], wz[4];
        #pragma unroll
        for (int ks = 0; ks < 4; ++ks) {
            wg[ks] = *(const bf16x8*)(wpg + ks * 512);
            wz[ks] = *(const bf16x8*)(wpz + ks * 512);
        }
        #pragma unroll
        for (int ks = 0; ks < 4; ++ks)
            #pragma unroll
            for (int t = 0; t < 2; ++t) {
                accg[t] = __builtin_amdgcn_mfma_f32_16x16x32_bf16(
                            afz[t][ks], wg[ks], accg[t], 0, 0, 0);
                accx[t] = __builtin_amdgcn_mfma_f32_16x16x32_bf16(
                            afx[t][ks], wz[ks], accx[t], 0, 0, 0);
            }
        #pragma unroll
        for (int t = 0; t < 2; ++t)
            #pragma unroll
            for (int r = 0; r < 4; ++r) {
                const size_t p = p0 + wave * 32 + t * 16 + q * 4 + r;
                out[p * CC + o] = accx[t][r] * sigm(accg[t][r]);
            }
    }
}

// ---------------------------------------------------------------------------
extern "C" void kernel_launch(void* const* d_in, const int* in_sizes, int n_in,
                              void* d_out, int out_size, void* d_ws, size_t ws_size,
                              hipStream_t stream)
{
    const float* z    = (const float*)d_in[0];
    const float* mask = (const float*)d_in[1];
    const float* wi   = (const float*)d_in[2];
    const float* bi   = (const float*)d_in[3];
    const float* apw  = (const float*)d_in[4];
    const float* apb  = (const float*)d_in[5];
    const float* agw  = (const float*)d_in[6];
    const float* agb  = (const float*)d_in[7];
    const float* bpw  = (const float*)d_in[8];
    const float* bpb  = (const float*)d_in[9];
    const float* bgw  = (const float*)d_in[10];
    const float* bgb  = (const float*)d_in[11];
    const float* gw   = (const float*)d_in[12];
    const float* gb   = (const float*)d_in[13];
    const float* zw   = (const float*)d_in[14];
    const float* zb   = (const float*)d_in[15];
    const float* wo   = (const float*)d_in[16];
    const float* bo   = (const float*)d_in[17];

    u16* a_cm = (u16*)d_ws;                          // [c][CPITCH] bf16
    u16* b_cm = a_cm + (size_t)CC * CPITCH;
    u16* x_cm = b_cm + (size_t)CC * CPITCH;
    u16* w_pk = x_cm + (size_t)CC * CPITCH;          // 192 KiB packed frags
    u16* zn_pm = w_pk + (size_t)6 * 16384;           // 64 MiB zn handoff
    float* out = (float*)d_out;

    const size_t need_zn =
        ((size_t)CC * CPITCH * 3 + 6 * 16384 + (size_t)NPOS * CC) * sizeof(u16);
    const bool use_zn = (ws_size == 0) || (ws_size >= need_zn);
    if (!use_zn) zn_pm = nullptr;

    W6 w6; w6.p[0] = agw; w6.p[1] = apw; w6.p[2] = bgw; w6.p[3] = bpw;
    w6.p[4] = gw; w6.p[5] = zw;

    k0_pack<<<6 * 16384 / 256, 256, 0, stream>>>(w6, w_pk);
    k1_ln_proj<<<NPOS / 128, 512, 0, stream>>>(z, mask, wi, bi, w_pk,
                                               agb, apb, bgb, bpb, a_cm, b_cm, zn_pm);
    k2_gemm<<<128 * 16, 256, 0, stream>>>(a_cm, b_cm, x_cm);
    if (use_zn)
        k3_out_zn<<<NPOS / 128, 256, 0, stream>>>(out, x_cm, zn_pm, wo, bo,
                                                  w_pk, gb, zb);
    else
        k3_out<<<NPOS / 128, 256, 0, stream>>>(out, x_cm, z, wi, bi, wo, bo,
                                               w_pk, gb, zb);
}

// Round 9
// 479.972 us; speedup vs baseline: 1.0023x; 1.0023x over previous
//
#include <hip/hip_runtime.h>
#include <stddef.h>

#define NN 512
#define CC 128
#define NPOS (NN*NN)
#define CPITCH (NPOS + 512)

typedef unsigned short u16;
typedef unsigned int   u32;
typedef u16  u16x4  __attribute__((ext_vector_type(4)));
typedef u16  u16x8  __attribute__((ext_vector_type(8)));
typedef __bf16 bf16x8 __attribute__((ext_vector_type(8)));
typedef float f32x4  __attribute__((ext_vector_type(4)));

__device__ __forceinline__ float b2f(u16 u) {
    union { u32 i; float f; } w; w.i = ((u32)u) << 16; return w.f;
}
__device__ __forceinline__ u16 f2b(float f) {
    return __builtin_bit_cast(u16, (__bf16)f);
}
__device__ __forceinline__ float sigm(float x) { return 1.0f / (1.0f + __expf(-x)); }

__device__ __forceinline__ void gld16(const u16* g, u16* l) {
    __builtin_amdgcn_global_load_lds(
        (const __attribute__((address_space(1))) u32*)g,
        (__attribute__((address_space(3))) u32*)l, 16, 0, 0);
}

struct W6 { const float* p[6]; };   // 0:agw 1:apw 2:bgw 3:bpw 4:gw 5:zw

// ---------------------------------------------------------------------------
// K0: pack 6 [128x128] f32 weight matrices into bf16 MFMA-fragment order.
// ---------------------------------------------------------------------------
__global__ __launch_bounds__(256) void k0_pack(W6 w, u16* __restrict__ dst)
{
    const int i = blockIdx.x * 256 + threadIdx.x;     // 6*16384 total
    const int mt = i >> 14, r = i & 16383;
    const int cb = r >> 11, ks = (r >> 9) & 3, lane = (r >> 3) & 63, j = r & 7;
    const int row = cb * 16 + (lane & 15);
    const int col = ks * 32 + (lane >> 4) * 8 + j;
    dst[i] = f2b(w.p[mt][row * 128 + col]);
}

// ---------------------------------------------------------------------------
// K1 (wave-owns-cb, weights-stationary): unchanged from R8 (best measured,
// 127 us). 512 threads / 128 positions; wave w owns cb=w, 16 weight frags
// register-resident; main loop has no global loads.
// ---------------------------------------------------------------------------
__global__ __launch_bounds__(512) void k1_ln_proj(
    const float* __restrict__ z,  const float* __restrict__ mask,
    const float* __restrict__ wi, const float* __restrict__ bi,
    const u16* __restrict__ wpk,
    const float* __restrict__ agb, const float* __restrict__ apb,
    const float* __restrict__ bgb, const float* __restrict__ bpb,
    u16* __restrict__ a_cm, u16* __restrict__ b_cm,
    u16* __restrict__ zn_pm)
{
    __shared__ u16   zn[128][136];   // bf16 normalized z, pitch 136 (34.8 KB)
    __shared__ float mk_lds[128];
    const int tid = threadIdx.x;
    const size_t p0 = (size_t)blockIdx.x * 128;

    if (tid < 128) mk_lds[tid] = mask[p0 + tid];

    {   // ---- LayerNorm: 16 groups of 32 lanes; group g owns rows h*16+g ----
        const int g  = tid >> 5;            // 0..15
        const int c4 = (tid & 31) * 4;      // channel base
        const f32x4 wi4 = *(const f32x4*)(wi + c4);
        const f32x4 bi4 = *(const f32x4*)(bi + c4);
        f32x4 v[8];
        #pragma unroll
        for (int h = 0; h < 8; ++h)
            v[h] = *(const f32x4*)(z + (p0 + h * 16 + g) * CC + c4);
        #pragma unroll
        for (int h = 0; h < 8; ++h) {
            float s  = (v[h][0] + v[h][1]) + (v[h][2] + v[h][3]);
            float s2 = (v[h][0]*v[h][0] + v[h][1]*v[h][1])
                     + (v[h][2]*v[h][2] + v[h][3]*v[h][3]);
            #pragma unroll
            for (int ms = 1; ms <= 16; ms <<= 1) {
                s  += __shfl_xor(s,  ms);
                s2 += __shfl_xor(s2, ms);
            }
            const float mu   = s * (1.0f / CC);
            const float rstd = rsqrtf(s2 * (1.0f / CC) - mu * mu + 1e-5f);
            u16x4 o4;
            #pragma unroll
            for (int e = 0; e < 4; ++e) {
                const float nw = rstd * wi4[e];
                o4[e] = f2b(v[h][e] * nw + __builtin_fmaf(-mu, nw, bi4[e]));
            }
            const int row = h * 16 + g;
            *(u16x4*)&zn[row][c4] = o4;
            if (zn_pm)
                *(u16x4*)(zn_pm + (p0 + row) * CC + c4) = o4;
        }
    }

    const int wave = tid >> 6, lane = tid & 63;
    const int m = lane & 15, q = lane >> 4;
    const int cb = wave;
    const int o  = cb * 16 + m;

    bf16x8 wreg[4][4];                   // [matrix][ks] = 64 VGPR
    float  bias4[4];
    {
        const float* Bv[4] = { agb, apb, bgb, bpb };
        #pragma unroll
        for (int mt = 0; mt < 4; ++mt) {
            bias4[mt] = Bv[mt][o];
            const u16* wp = wpk + ((size_t)((mt * 8 + cb) * 4)) * 512
                                + (size_t)lane * 8;
            #pragma unroll
            for (int ks = 0; ks < 4; ++ks)
                wreg[mt][ks] = *(const bf16x8*)(wp + ks * 512);
        }
    }
    __syncthreads();

    #pragma unroll 2
    for (int t = 0; t < 8; ++t) {
        bf16x8 af[4];
        #pragma unroll
        for (int ks = 0; ks < 4; ++ks)
            af[ks] = *(const bf16x8*)&zn[t * 16 + m][ks * 32 + q * 8];
        const f32x4 mk4 = *(const f32x4*)&mk_lds[t * 16 + q * 4];

        f32x4 res[4];
        #pragma unroll
        for (int mt = 0; mt < 4; ++mt) {
            const float bv = bias4[mt];
            res[mt] = f32x4{ bv, bv, bv, bv };
        }
        #pragma unroll
        for (int ks = 0; ks < 4; ++ks)
            #pragma unroll
            for (int mt = 0; mt < 4; ++mt)
                res[mt] = __builtin_amdgcn_mfma_f32_16x16x32_bf16(
                            af[ks], wreg[mt][ks], res[mt], 0, 0, 0);

        u16x4 av, bv;
        #pragma unroll
        for (int r = 0; r < 4; ++r) {
            const float mk = mk4[r];
            av[r] = f2b(mk * sigm(res[0][r]) * res[1][r]);
            bv[r] = f2b(mk * sigm(res[2][r]) * res[3][r]);
        }
        const size_t off = (size_t)o * CPITCH + p0 + t * 16 + q * 4;
        *(u16x4*)(a_cm + off) = av;
        *(u16x4*)(b_cm + off) = bv;
    }
}

// ---------------------------------------------------------------------------
// K2: per-channel 512x512x512 NT GEMM, XCD-affine.
// NEW (T4): counted-vmcnt pipeline. R7's __syncthreads drained vmcnt(0),
// forcing the just-issued next-tile loads to COMPLETE inside every barrier.
// Now: issue next tile -> s_waitcnt vmcnt(4) (wait only current tile's 4
// loads; next tile's 4 stay in flight; vmcnt retires in order) -> raw
// s_barrier -> compute -> raw s_barrier (protects buffer from kt+2
// overwrite). sched_barrier(0) fences keep the compiler from hoisting LDS
// reads across the raw barriers (rule #18).
// ---------------------------------------------------------------------------
__global__ __launch_bounds__(256) void k2_gemm(
    const u16* __restrict__ A, const u16* __restrict__ B, u16* __restrict__ X)
{
    __shared__ u16 As[2][128][32];
    __shared__ u16 Bs[2][128][32];
    const int tid = threadIdx.x;
    const int bx  = blockIdx.x;
    const int xcd  = bx & 7;
    const int slot = bx >> 3;              // 0..255 per XCD
    const int c    = (slot >> 4) * 8 + xcd;
    const int tile = slot & 15;
    const int i0   = (tile >> 2) * 128;
    const int j0   = (tile & 3) * 128;
    const size_t cbase = (size_t)c * CPITCH;
    const u16* Ac = A + cbase;
    const u16* Bc = B + cbase;

    const int wave = tid >> 6, lane = tid & 63;
    const int wm = wave >> 1, wn = wave & 1;
    const int m = lane & 15, q = lane >> 4;

    f32x4 acc[4][4];
    const f32x4 zero = { 0.f, 0.f, 0.f, 0.f };
    #pragma unroll
    for (int mt = 0; mt < 4; ++mt)
        #pragma unroll
        for (int nt = 0; nt < 4; ++nt) acc[mt][nt] = zero;

    // 4 gld16/thread per tile (2 ps x {A,B}); vmcnt-ordered.
    auto stage = [&](int kt, int buf) {
        #pragma unroll
        for (int ps = 0; ps < 2; ++ps) {
            const int id = ps * 256 + tid;
            const int rw = id >> 2;
            const int g  = (id & 3) ^ ((rw >> 1) & 3);
            const size_t goff = (size_t)(kt * 32 + g * 8);
            gld16(Ac + (size_t)(i0 + rw) * NN + goff, &As[buf][0][0] + id * 8);
            gld16(Bc + (size_t)(j0 + rw) * NN + goff, &Bs[buf][0][0] + id * 8);
        }
    };
    auto compute = [&](int buf) {
        bf16x8 af[4], bf[4];
        #pragma unroll
        for (int mt = 0; mt < 4; ++mt) {
            const int row = wm * 64 + mt * 16 + m;
            const int slt = q ^ ((row >> 1) & 3);
            af[mt] = *(const bf16x8*)&As[buf][row][slt * 8];
        }
        #pragma unroll
        for (int nt = 0; nt < 4; ++nt) {
            const int row = wn * 64 + nt * 16 + m;
            const int slt = q ^ ((row >> 1) & 3);
            bf[nt] = *(const bf16x8*)&Bs[buf][row][slt * 8];
        }
        #pragma unroll
        for (int mt = 0; mt < 4; ++mt)
            #pragma unroll
            for (int nt = 0; nt < 4; ++nt)
                acc[mt][nt] = __builtin_amdgcn_mfma_f32_16x16x32_bf16(
                                af[mt], bf[nt], acc[mt][nt], 0, 0, 0);
    };

    stage(0, 0);
    int cur = 0;
    for (int kt = 0; kt < 15; ++kt) {
        stage(kt + 1, cur ^ 1);
        asm volatile("s_waitcnt vmcnt(4)" ::: "memory");
        __builtin_amdgcn_s_barrier();          // tile kt fully in LDS
        __builtin_amdgcn_sched_barrier(0);
        compute(cur);
        __builtin_amdgcn_sched_barrier(0);
        __builtin_amdgcn_s_barrier();          // all reads of buf cur done
        cur ^= 1;
    }
    asm volatile("s_waitcnt vmcnt(0)" ::: "memory");
    __builtin_amdgcn_s_barrier();
    __builtin_amdgcn_sched_barrier(0);
    compute(cur);                               // tile 15

    #pragma unroll
    for (int mt = 0; mt < 4; ++mt) {
        #pragma unroll
        for (int r = 0; r < 4; ++r) {
            const int i = i0 + wm * 64 + mt * 16 + q * 4 + r;
            #pragma unroll
            for (int nt = 0; nt < 4; ++nt) {
                const int j = j0 + wn * 64 + nt * 16 + m;
                X[cbase + (size_t)i * NN + j] = f2b(acc[mt][nt][r]);
            }
        }
    }
}

// ---------------------------------------------------------------------------
// K3: out = (LN(x)@z_w^T + z_b) * sigmoid(zn@g_w^T + g_b), zn from handoff.
// r4 version (best measured). Unchanged.
// ---------------------------------------------------------------------------
__global__ __launch_bounds__(256) void k3_out_zn(
    float* __restrict__ out, const u16* __restrict__ x_cm,
    const u16* __restrict__ zn_pm,
    const float* __restrict__ wo, const float* __restrict__ bo,
    const u16* __restrict__ wpk,
    const float* __restrict__ gbv, const float* __restrict__ zbv)
{
    __shared__ u16 A[128][136];    // xn
    __shared__ u16 Bt[128][136];   // x tile, channel-major [c][p]
    const int tid = threadIdx.x;
    const size_t p0 = (size_t)blockIdx.x * 128;
    const int wave = tid >> 6, lane = tid & 63;
    const int m = lane & 15, q = lane >> 4;
    const int pl = tid >> 1, ht = tid & 1;

    {
        const int c = tid >> 1, seg = tid & 1;
        #pragma unroll
        for (int e = 0; e < 8; ++e) {
            u16x8 vv = *(const u16x8*)(x_cm + (size_t)c * CPITCH + p0 + seg * 64 + e * 8);
            *(u16x8*)&Bt[c][seg * 64 + e * 8] = vv;
        }
    }
    bf16x8 afz[2][4];
    #pragma unroll
    for (int t = 0; t < 2; ++t)
        #pragma unroll
        for (int ks = 0; ks < 4; ++ks)
            afz[t][ks] = *(const bf16x8*)(zn_pm
                           + (p0 + wave * 32 + t * 16 + m) * CC + ks * 32 + q * 8);
    __syncthreads();

    {
        float v[64];
        #pragma unroll
        for (int e = 0; e < 64; ++e) v[e] = b2f(Bt[ht * 64 + e][pl]);
        float s = 0.f, s2 = 0.f;
        #pragma unroll
        for (int e = 0; e < 64; ++e) { s += v[e]; s2 += v[e] * v[e]; }
        s  += __shfl_xor(s, 1);
        s2 += __shfl_xor(s2, 1);
        const float mu   = s * (1.0f / CC);
        const float rstd = rsqrtf(s2 * (1.0f / CC) - mu * mu + 1e-5f);
        #pragma unroll
        for (int h = 0; h < 8; ++h) {
            u16x8 o8;
            #pragma unroll
            for (int e = 0; e < 8; ++e) {
                const int c = ht * 64 + h * 8 + e;
                o8[e] = f2b((v[h * 8 + e] - mu) * rstd * wo[c] + bo[c]);
            }
            *(u16x8*)&A[pl][ht * 64 + h * 8] = o8;
        }
    }
    __syncthreads();

    bf16x8 afx[2][4];
    #pragma unroll
    for (int t = 0; t < 2; ++t)
        #pragma unroll
        for (int ks = 0; ks < 4; ++ks)
            afx[t][ks] = *(const bf16x8*)&A[wave * 32 + t * 16 + m][ks * 32 + q * 8];

    for (int cb = 0; cb < 8; ++cb) {
        const int o = cb * 16 + m;
        const float gb0 = gbv[o], zb0 = zbv[o];
        f32x4 accg[2], accx[2];
        #pragma unroll
        for (int t = 0; t < 2; ++t) {
            accg[t] = f32x4{ gb0, gb0, gb0, gb0 };
            accx[t] = f32x4{ zb0, zb0, zb0, zb0 };
        }
        const u16* wpg = wpk + ((size_t)((4 * 8 + cb) * 4)) * 512 + (size_t)lane * 8;
        const u16* wpz = wpk + ((size_t)((5 * 8 + cb) * 4)) * 512 + (size_t)lane * 8;
        bf16x8 wg[4], wz[4];
        #pragma unroll
        for (int ks = 0; ks < 4; ++ks) {
            wg[ks] = *(const bf16x8*)(wpg + ks * 512);
            wz[ks] = *(const bf16x8*)(wpz + ks * 512);
        }
        #pragma unroll
        for (int ks = 0; ks < 4; ++ks)
            #pragma unroll
            for (int t = 0; t < 2; ++t) {
                accg[t] = __builtin_amdgcn_mfma_f32_16x16x32_bf16(
                            afz[t][ks], wg[ks], accg[t], 0, 0, 0);
                accx[t] = __builtin_amdgcn_mfma_f32_16x16x32_bf16(
                            afx[t][ks], wz[ks], accx[t], 0, 0, 0);
            }
        #pragma unroll
        for (int t = 0; t < 2; ++t)
            #pragma unroll
            for (int r = 0; r < 4; ++r) {
                const size_t p = p0 + wave * 32 + t * 16 + q * 4 + r;
                out[p * CC + o] = accx[t][r] * sigm(accg[t][r]);
            }
    }
}

// ---------------------------------------------------------------------------
// K3 (legacy fallback, used only if workspace too small for zn handoff).
// ---------------------------------------------------------------------------
__global__ __launch_bounds__(256) void k3_out(
    float* __restrict__ out, const u16* __restrict__ x_cm,
    const float* __restrict__ z,
    const float* __restrict__ wi, const float* __restrict__ bi,
    const float* __restrict__ wo, const float* __restrict__ bo,
    const u16* __restrict__ wpk,
    const float* __restrict__ gbv, const float* __restrict__ zbv)
{
    __shared__ u16 A[128][136];
    __shared__ u16 Bt[128][136];
    const int tid = threadIdx.x;
    const size_t p0 = (size_t)blockIdx.x * 128;
    const int wave = tid >> 6, lane = tid & 63;
    const int m = lane & 15, q = lane >> 4;
    const int pl = tid >> 1, ht = tid & 1;

    {
        const float* zr = z + (p0 + pl) * CC + ht * 64;
        float v[64];
        #pragma unroll
        for (int h = 0; h < 16; ++h) {
            f32x4 t = *(const f32x4*)(zr + h * 4);
            #pragma unroll
            for (int e = 0; e < 4; ++e) v[h * 4 + e] = t[e];
        }
        float s = 0.f, s2 = 0.f;
        #pragma unroll
        for (int e = 0; e < 64; ++e) { s += v[e]; s2 += v[e] * v[e]; }
        s  += __shfl_xor(s, 1);
        s2 += __shfl_xor(s2, 1);
        const float mu   = s * (1.0f / CC);
        const float rstd = rsqrtf(s2 * (1.0f / CC) - mu * mu + 1e-5f);
        #pragma unroll
        for (int h = 0; h < 8; ++h) {
            u16x8 o8;
            #pragma unroll
            for (int e = 0; e < 8; ++e) {
                const int c = ht * 64 + h * 8 + e;
                o8[e] = f2b((v[h * 8 + e] - mu) * rstd * wi[c] + bi[c]);
            }
            *(u16x8*)&A[pl][ht * 64 + h * 8] = o8;
        }
    }
    {
        const int c = tid >> 1, seg = tid & 1;
        #pragma unroll
        for (int e = 0; e < 8; ++e) {
            u16x8 vv = *(const u16x8*)(x_cm + (size_t)c * CPITCH + p0 + seg * 64 + e * 8);
            *(u16x8*)&Bt[c][seg * 64 + e * 8] = vv;
        }
    }
    __syncthreads();

    bf16x8 afz[2][4];
    #pragma unroll
    for (int t = 0; t < 2; ++t)
        #pragma unroll
        for (int ks = 0; ks < 4; ++ks)
            afz[t][ks] = *(const bf16x8*)&A[wave * 32 + t * 16 + m][ks * 32 + q * 8];
    __syncthreads();

    {
        float v[64];
        #pragma unroll
        for (int e = 0; e < 64; ++e) v[e] = b2f(Bt[ht * 64 + e][pl]);
        float s = 0.f, s2 = 0.f;
        #pragma unroll
        for (int e = 0; e < 64; ++e) { s += v[e]; s2 += v[e] * v[e]; }
        s  += __shfl_xor(s, 1);
        s2 += __shfl_xor(s2, 1);
        const float mu   = s * (1.0f / CC);
        const float rstd = rsqrtf(s2 * (1.0f / CC) - mu * mu + 1e-5f);
        #pragma unroll
        for (int h = 0; h < 8; ++h) {
            u16x8 o8;
            #pragma unroll
            for (int e = 0; e < 8; ++e) {
                const int c = ht * 64 + h * 8 + e;
                o8[e] = f2b((v[h * 8 + e] - mu) * rstd * wo[c] + bo[c]);
            }
            *(u16x8*)&A[pl][ht * 64 + h * 8] = o8;
        }
    }
    __syncthreads();

    bf16x8 afx[2][4];
    #pragma unroll
    for (int t = 0; t < 2; ++t)
        #pragma unroll
        for (int ks = 0; ks < 4; ++ks)
            afx[t][ks] = *(const bf16x8*)&A[wave * 32 + t * 16 + m][ks * 32 + q * 8];

    for (int cb = 0; cb < 8; ++cb) {
        const int o = cb * 16 + m;
        const float gb0 = gbv[o], zb0 = zbv[o];
        f32x4 accg[2], accx[2];
        #pragma unroll
        for (int t = 0; t < 2; ++t) {
            accg[t] = f32x4{ gb0, gb0, gb0, gb0 };
            accx[t] = f32x4{ zb0, zb0, zb0, zb0 };
        }
        const u16* wpg = wpk + ((size_t)((4 * 8 + cb) * 4)) * 512 + (size_t)lane * 8;
        const u16* wpz = wpk + ((size_t)((5 * 8 + cb) * 4)) * 512 + (size_t)lane * 8;
        bf16x8 wg[4], wz[4];
        #pragma unroll
        for (int ks = 0; ks < 4; ++ks) {
            wg[ks] = *(const bf16x8*)(wpg + ks * 512);
            wz[ks] = *(const bf16x8*)(wpz + ks * 512);
        }
        #pragma unroll
        for (int ks = 0; ks < 4; ++ks)
            #pragma unroll
            for (int t = 0; t < 2; ++t) {
                accg[t] = __builtin_amdgcn_mfma_f32_16x16x32_bf16(
                            afz[t][ks], wg[ks], accg[t], 0, 0, 0);
                accx[t] = __builtin_amdgcn_mfma_f32_16x16x32_bf16(
                            afx[t][ks], wz[ks], accx[t], 0, 0, 0);
            }
        #pragma unroll
        for (int t = 0; t < 2; ++t)
            #pragma unroll
            for (int r = 0; r < 4; ++r) {
                const size_t p = p0 + wave * 32 + t * 16 + q * 4 + r;
                out[p * CC + o] = accx[t][r] * sigm(accg[t][r]);
            }
    }
}

// ---------------------------------------------------------------------------
extern "C" void kernel_launch(void* const* d_in, const int* in_sizes, int n_in,
                              void* d_out, int out_size, void* d_ws, size_t ws_size,
                              hipStream_t stream)
{
    const float* z    = (const float*)d_in[0];
    const float* mask = (const float*)d_in[1];
    const float* wi   = (const float*)d_in[2];
    const float* bi   = (const float*)d_in[3];
    const float* apw  = (const float*)d_in[4];
    const float* apb  = (const float*)d_in[5];
    const float* agw  = (const float*)d_in[6];
    const float* agb  = (const float*)d_in[7];
    const float* bpw  = (const float*)d_in[8];
    const float* bpb  = (const float*)d_in[9];
    const float* bgw  = (const float*)d_in[10];
    const float* bgb  = (const float*)d_in[11];
    const float* gw   = (const float*)d_in[12];
    const float* gb   = (const float*)d_in[13];
    const float* zw   = (const float*)d_in[14];
    const float* zb   = (const float*)d_in[15];
    const float* wo   = (const float*)d_in[16];
    const float* bo   = (const float*)d_in[17];

    u16* a_cm = (u16*)d_ws;                          // [c][CPITCH] bf16
    u16* b_cm = a_cm + (size_t)CC * CPITCH;
    u16* x_cm = b_cm + (size_t)CC * CPITCH;
    u16* w_pk = x_cm + (size_t)CC * CPITCH;          // 192 KiB packed frags
    u16* zn_pm = w_pk + (size_t)6 * 16384;           // 64 MiB zn handoff
    float* out = (float*)d_out;

    const size_t need_zn =
        ((size_t)CC * CPITCH * 3 + 6 * 16384 + (size_t)NPOS * CC) * sizeof(u16);
    const bool use_zn = (ws_size == 0) || (ws_size >= need_zn);
    if (!use_zn) zn_pm = nullptr;

    W6 w6; w6.p[0] = agw; w6.p[1] = apw; w6.p[2] = bgw; w6.p[3] = bpw;
    w6.p[4] = gw; w6.p[5] = zw;

    k0_pack<<<6 * 16384 / 256, 256, 0, stream>>>(w6, w_pk);
    k1_ln_proj<<<NPOS / 128, 512, 0, stream>>>(z, mask, wi, bi, w_pk,
                                               agb, apb, bgb, bpb, a_cm, b_cm, zn_pm);
    k2_gemm<<<128 * 16, 256, 0, stream>>>(a_cm, b_cm, x_cm);
    if (use_zn)
        k3_out_zn<<<NPOS / 128, 256, 0, stream>>>(out, x_cm, zn_pm, wo, bo,
                                                  w_pk, gb, zb);
    else
        k3_out<<<NPOS / 128, 256, 0, stream>>>(out, x_cm, z, wi, bi, wo, bo,
                                               w_pk, gb, zb);
}

// Round 10
// 476.952 us; speedup vs baseline: 1.0087x; 1.0063x over previous
//
#include <hip/hip_runtime.h>
#include <stddef.h>

#define NN 512
#define CC 128
#define NPOS (NN*NN)
#define CPITCH (NPOS + 512)

typedef unsigned short u16;
typedef unsigned int   u32;
typedef u16  u16x4  __attribute__((ext_vector_type(4)));
typedef u16  u16x8  __attribute__((ext_vector_type(8)));
typedef __bf16 bf16x8 __attribute__((ext_vector_type(8)));
typedef float f32x4  __attribute__((ext_vector_type(4)));

__device__ __forceinline__ float b2f(u16 u) {
    union { u32 i; float f; } w; w.i = ((u32)u) << 16; return w.f;
}
__device__ __forceinline__ u16 f2b(float f) {
    return __builtin_bit_cast(u16, (__bf16)f);
}
__device__ __forceinline__ float sigm(float x) { return 1.0f / (1.0f + __expf(-x)); }

__device__ __forceinline__ void gld16(const u16* g, u16* l) {
    __builtin_amdgcn_global_load_lds(
        (const __attribute__((address_space(1))) u32*)g,
        (__attribute__((address_space(3))) u32*)l, 16, 0, 0);
}

struct W6 { const float* p[6]; };   // 0:agw 1:apw 2:bgw 3:bpw 4:gw 5:zw

// ---------------------------------------------------------------------------
// K0: pack 6 [128x128] f32 weight matrices into bf16 MFMA-fragment order.
// ---------------------------------------------------------------------------
__global__ __launch_bounds__(256) void k0_pack(W6 w, u16* __restrict__ dst)
{
    const int i = blockIdx.x * 256 + threadIdx.x;     // 6*16384 total
    const int mt = i >> 14, r = i & 16383;
    const int cb = r >> 11, ks = (r >> 9) & 3, lane = (r >> 3) & 63, j = r & 7;
    const int row = cb * 16 + (lane & 15);
    const int col = ks * 32 + (lane >> 4) * 8 + j;
    dst[i] = f2b(w.p[mt][row * 128 + col]);
}

// ---------------------------------------------------------------------------
// K1 (wave-owns-cb, weights-stationary): unchanged from R8/R9 (best, 126 us).
// ---------------------------------------------------------------------------
__global__ __launch_bounds__(512) void k1_ln_proj(
    const float* __restrict__ z,  const float* __restrict__ mask,
    const float* __restrict__ wi, const float* __restrict__ bi,
    const u16* __restrict__ wpk,
    const float* __restrict__ agb, const float* __restrict__ apb,
    const float* __restrict__ bgb, const float* __restrict__ bpb,
    u16* __restrict__ a_cm, u16* __restrict__ b_cm,
    u16* __restrict__ zn_pm)
{
    __shared__ u16   zn[128][136];   // bf16 normalized z, pitch 136 (34.8 KB)
    __shared__ float mk_lds[128];
    const int tid = threadIdx.x;
    const size_t p0 = (size_t)blockIdx.x * 128;

    if (tid < 128) mk_lds[tid] = mask[p0 + tid];

    {   // ---- LayerNorm: 16 groups of 32 lanes; group g owns rows h*16+g ----
        const int g  = tid >> 5;            // 0..15
        const int c4 = (tid & 31) * 4;      // channel base
        const f32x4 wi4 = *(const f32x4*)(wi + c4);
        const f32x4 bi4 = *(const f32x4*)(bi + c4);
        f32x4 v[8];
        #pragma unroll
        for (int h = 0; h < 8; ++h)
            v[h] = *(const f32x4*)(z + (p0 + h * 16 + g) * CC + c4);
        #pragma unroll
        for (int h = 0; h < 8; ++h) {
            float s  = (v[h][0] + v[h][1]) + (v[h][2] + v[h][3]);
            float s2 = (v[h][0]*v[h][0] + v[h][1]*v[h][1])
                     + (v[h][2]*v[h][2] + v[h][3]*v[h][3]);
            #pragma unroll
            for (int ms = 1; ms <= 16; ms <<= 1) {
                s  += __shfl_xor(s,  ms);
                s2 += __shfl_xor(s2, ms);
            }
            const float mu   = s * (1.0f / CC);
            const float rstd = rsqrtf(s2 * (1.0f / CC) - mu * mu + 1e-5f);
            u16x4 o4;
            #pragma unroll
            for (int e = 0; e < 4; ++e) {
                const float nw = rstd * wi4[e];
                o4[e] = f2b(v[h][e] * nw + __builtin_fmaf(-mu, nw, bi4[e]));
            }
            const int row = h * 16 + g;
            *(u16x4*)&zn[row][c4] = o4;
            if (zn_pm)
                *(u16x4*)(zn_pm + (p0 + row) * CC + c4) = o4;
        }
    }

    const int wave = tid >> 6, lane = tid & 63;
    const int m = lane & 15, q = lane >> 4;
    const int cb = wave;
    const int o  = cb * 16 + m;

    bf16x8 wreg[4][4];                   // [matrix][ks] = 64 VGPR
    float  bias4[4];
    {
        const float* Bv[4] = { agb, apb, bgb, bpb };
        #pragma unroll
        for (int mt = 0; mt < 4; ++mt) {
            bias4[mt] = Bv[mt][o];
            const u16* wp = wpk + ((size_t)((mt * 8 + cb) * 4)) * 512
                                + (size_t)lane * 8;
            #pragma unroll
            for (int ks = 0; ks < 4; ++ks)
                wreg[mt][ks] = *(const bf16x8*)(wp + ks * 512);
        }
    }
    __syncthreads();

    #pragma unroll 2
    for (int t = 0; t < 8; ++t) {
        bf16x8 af[4];
        #pragma unroll
        for (int ks = 0; ks < 4; ++ks)
            af[ks] = *(const bf16x8*)&zn[t * 16 + m][ks * 32 + q * 8];
        const f32x4 mk4 = *(const f32x4*)&mk_lds[t * 16 + q * 4];

        f32x4 res[4];
        #pragma unroll
        for (int mt = 0; mt < 4; ++mt) {
            const float bv = bias4[mt];
            res[mt] = f32x4{ bv, bv, bv, bv };
        }
        #pragma unroll
        for (int ks = 0; ks < 4; ++ks)
            #pragma unroll
            for (int mt = 0; mt < 4; ++mt)
                res[mt] = __builtin_amdgcn_mfma_f32_16x16x32_bf16(
                            af[ks], wreg[mt][ks], res[mt], 0, 0, 0);

        u16x4 av, bv;
        #pragma unroll
        for (int r = 0; r < 4; ++r) {
            const float mk = mk4[r];
            av[r] = f2b(mk * sigm(res[0][r]) * res[1][r]);
            bv[r] = f2b(mk * sigm(res[2][r]) * res[3][r]);
        }
        const size_t off = (size_t)o * CPITCH + p0 + t * 16 + q * 4;
        *(u16x4*)(a_cm + off) = av;
        *(u16x4*)(b_cm + off) = bv;
    }
}

// ---------------------------------------------------------------------------
// K2: per-channel NT GEMM, XCD-affine, counted-vmcnt pipeline (R9, unchanged).
// ---------------------------------------------------------------------------
__global__ __launch_bounds__(256) void k2_gemm(
    const u16* __restrict__ A, const u16* __restrict__ B, u16* __restrict__ X)
{
    __shared__ u16 As[2][128][32];
    __shared__ u16 Bs[2][128][32];
    const int tid = threadIdx.x;
    const int bx  = blockIdx.x;
    const int xcd  = bx & 7;
    const int slot = bx >> 3;              // 0..255 per XCD
    const int c    = (slot >> 4) * 8 + xcd;
    const int tile = slot & 15;
    const int i0   = (tile >> 2) * 128;
    const int j0   = (tile & 3) * 128;
    const size_t cbase = (size_t)c * CPITCH;
    const u16* Ac = A + cbase;
    const u16* Bc = B + cbase;

    const int wave = tid >> 6, lane = tid & 63;
    const int wm = wave >> 1, wn = wave & 1;
    const int m = lane & 15, q = lane >> 4;

    f32x4 acc[4][4];
    const f32x4 zero = { 0.f, 0.f, 0.f, 0.f };
    #pragma unroll
    for (int mt = 0; mt < 4; ++mt)
        #pragma unroll
        for (int nt = 0; nt < 4; ++nt) acc[mt][nt] = zero;

    auto stage = [&](int kt, int buf) {
        #pragma unroll
        for (int ps = 0; ps < 2; ++ps) {
            const int id = ps * 256 + tid;
            const int rw = id >> 2;
            const int g  = (id & 3) ^ ((rw >> 1) & 3);
            const size_t goff = (size_t)(kt * 32 + g * 8);
            gld16(Ac + (size_t)(i0 + rw) * NN + goff, &As[buf][0][0] + id * 8);
            gld16(Bc + (size_t)(j0 + rw) * NN + goff, &Bs[buf][0][0] + id * 8);
        }
    };
    auto compute = [&](int buf) {
        bf16x8 af[4], bf[4];
        #pragma unroll
        for (int mt = 0; mt < 4; ++mt) {
            const int row = wm * 64 + mt * 16 + m;
            const int slt = q ^ ((row >> 1) & 3);
            af[mt] = *(const bf16x8*)&As[buf][row][slt * 8];
        }
        #pragma unroll
        for (int nt = 0; nt < 4; ++nt) {
            const int row = wn * 64 + nt * 16 + m;
            const int slt = q ^ ((row >> 1) & 3);
            bf[nt] = *(const bf16x8*)&Bs[buf][row][slt * 8];
        }
        #pragma unroll
        for (int mt = 0; mt < 4; ++mt)
            #pragma unroll
            for (int nt = 0; nt < 4; ++nt)
                acc[mt][nt] = __builtin_amdgcn_mfma_f32_16x16x32_bf16(
                                af[mt], bf[nt], acc[mt][nt], 0, 0, 0);
    };

    stage(0, 0);
    int cur = 0;
    for (int kt = 0; kt < 15; ++kt) {
        stage(kt + 1, cur ^ 1);
        asm volatile("s_waitcnt vmcnt(4)" ::: "memory");
        __builtin_amdgcn_s_barrier();
        __builtin_amdgcn_sched_barrier(0);
        compute(cur);
        __builtin_amdgcn_sched_barrier(0);
        __builtin_amdgcn_s_barrier();
        cur ^= 1;
    }
    asm volatile("s_waitcnt vmcnt(0)" ::: "memory");
    __builtin_amdgcn_s_barrier();
    __builtin_amdgcn_sched_barrier(0);
    compute(cur);

    #pragma unroll
    for (int mt = 0; mt < 4; ++mt) {
        #pragma unroll
        for (int r = 0; r < 4; ++r) {
            const int i = i0 + wm * 64 + mt * 16 + q * 4 + r;
            #pragma unroll
            for (int nt = 0; nt < 4; ++nt) {
                const int j = j0 + wn * 64 + nt * 16 + m;
                X[cbase + (size_t)i * NN + j] = f2b(acc[mt][nt][r]);
            }
        }
    }
}

// ---------------------------------------------------------------------------
// K3 v3: out = (LN(x)@z_w^T + z_b) * sigmoid(zn@g_w^T + g_b)
// Rewritten with the proven k1 patterns:
//  - single 33.8 KB LDS buffer XT[128][132] position-major (was 2x34.8 KB)
//  - swizzled scalar-scatter transpose at stage time (conflict-free: the
//    32B-granular XOR key ((p>>5)&3)<<5 puts the 4 row-groups of each write
//    instruction in disjoint bank octets)
//  - parallel in-place LN (32-lane-group butterfly; no 64-deep serial chain,
//    no scalar column reads, one barrier fewer)
//  - wave-owns-cb: 8 waves x 1 cb; wg/wz loaded ONCE into registers
//  - af reads as paired ds_read_b64 (pitch 264B is 8B-aligned, bank stride 2)
// ---------------------------------------------------------------------------
#define XPITCH 132   // u16 per row (264 B; 66 dwords == 2 mod 32 banks)

__global__ __launch_bounds__(512) void k3_out_v3(
    float* __restrict__ out, const u16* __restrict__ x_cm,
    const u16* __restrict__ zn_pm,
    const float* __restrict__ wo, const float* __restrict__ bo,
    const u16* __restrict__ wpk,
    const float* __restrict__ gbv, const float* __restrict__ zbv)
{
    __shared__ u16 XT[128 * XPITCH];
    char* xt = (char*)XT;
    const int tid = threadIdx.x;
    const size_t p0 = (size_t)blockIdx.x * 128;
    const int wave = tid >> 6, lane = tid & 63;
    const int m = lane & 15, q = lane >> 4;

    // wave-owned weights: load once (hidden under staging)
    const int cb = wave, o = cb * 16 + m;
    const float gb0 = gbv[o], zb0 = zbv[o];
    bf16x8 wg[4], wz[4];
    {
        const u16* wpg = wpk + ((size_t)((4 * 8 + cb) * 4)) * 512 + (size_t)lane * 8;
        const u16* wpz = wpk + ((size_t)((5 * 8 + cb) * 4)) * 512 + (size_t)lane * 8;
        #pragma unroll
        for (int ks = 0; ks < 4; ++ks) {
            wg[ks] = *(const bf16x8*)(wpg + ks * 512);
            wz[ks] = *(const bf16x8*)(wpz + ks * 512);
        }
    }
    // prefetch first tile's gate fragments (global, independent of LDS)
    bf16x8 afz0[4];
    #pragma unroll
    for (int ks = 0; ks < 4; ++ks)
        afz0[ks] = *(const bf16x8*)(zn_pm + (p0 + m) * CC + ks * 32 + q * 8);

    // ---- stage x: coalesced global reads, swizzled scatter into XT ----
    // XB(p, cbyte) = p*264 + (cbyte ^ ((p>>5)&3)<<5)  -- all sites agree.
    {
        const int c   = tid >> 2;        // channel
        const int sg  = tid & 3;         // position group (32 rows); p>>5 == sg
        const int key = sg << 5;
        const int cx  = (c * 2) ^ key;
        #pragma unroll
        for (int l = 0; l < 4; ++l) {
            u16x8 vv = *(const u16x8*)(x_cm + (size_t)c * CPITCH
                                       + p0 + sg * 32 + l * 8);
            #pragma unroll
            for (int j = 0; j < 8; ++j) {
                const int p = sg * 32 + l * 8 + j;
                *(u16*)(xt + p * 264 + cx) = vv[j];
            }
        }
    }
    __syncthreads();

    // ---- LayerNorm in place: group g owns rows g*8 .. g*8+7 ----
    {
        const int g = tid >> 5, l32 = tid & 31;
        const int c4 = l32 * 4;
        const f32x4 wo4 = *(const f32x4*)(wo + c4);
        const f32x4 bo4 = *(const f32x4*)(bo + c4);
        #pragma unroll
        for (int h = 0; h < 8; ++h) {
            const int r  = g * 8 + h;
            const int ad = r * 264 + ((c4 * 2) ^ (((r >> 5) & 3) << 5));
            const u16x4 xv = *(const u16x4*)(xt + ad);
            const float x0 = b2f(xv[0]), x1 = b2f(xv[1]),
                        x2 = b2f(xv[2]), x3 = b2f(xv[3]);
            float s  = (x0 + x1) + (x2 + x3);
            float s2 = (x0*x0 + x1*x1) + (x2*x2 + x3*x3);
            #pragma unroll
            for (int ms = 1; ms <= 16; ms <<= 1) {
                s  += __shfl_xor(s,  ms);
                s2 += __shfl_xor(s2, ms);
            }
            const float mu   = s * (1.0f / CC);
            const float rstd = rsqrtf(s2 * (1.0f / CC) - mu * mu + 1e-5f);
            u16x4 o4;
            o4[0] = f2b((x0 - mu) * rstd * wo4[0] + bo4[0]);
            o4[1] = f2b((x1 - mu) * rstd * wo4[1] + bo4[1]);
            o4[2] = f2b((x2 - mu) * rstd * wo4[2] + bo4[2]);
            o4[3] = f2b((x3 - mu) * rstd * wo4[3] + bo4[3]);
            *(u16x4*)(xt + ad) = o4;
        }
    }
    __syncthreads();

    // ---- main loop: 8 position-tiles; wave computes its cb for all ----
    union B8 { struct { u16x4 lo, hi; } h; bf16x8 v; };
    #pragma unroll
    for (int t = 0; t < 8; ++t) {
        // gate fragments: current from prefetch, then prefetch next
        bf16x8 afz[4];
        #pragma unroll
        for (int ks = 0; ks < 4; ++ks) afz[ks] = afz0[ks];
        if (t < 7) {
            #pragma unroll
            for (int ks = 0; ks < 4; ++ks)
                afz0[ks] = *(const bf16x8*)(zn_pm + (p0 + (t + 1) * 16 + m) * CC
                                            + ks * 32 + q * 8);
        }
        // xn fragments from XT (paired b64, swizzled)
        const int key = ((t >> 1) & 3) << 5;
        const int rowb = (t * 16 + m) * 264;
        bf16x8 afx[4];
        #pragma unroll
        for (int ks = 0; ks < 4; ++ks) {
            B8 u;
            const int cbyte = (ks * 64 + q * 16) ^ key;
            u.h.lo = *(const u16x4*)(xt + rowb + cbyte);
            u.h.hi = *(const u16x4*)(xt + rowb + cbyte + 8);
            afx[ks] = u.v;
        }
        f32x4 accg = { gb0, gb0, gb0, gb0 };
        f32x4 accx = { zb0, zb0, zb0, zb0 };
        #pragma unroll
        for (int ks = 0; ks < 4; ++ks) {
            accg = __builtin_amdgcn_mfma_f32_16x16x32_bf16(afz[ks], wg[ks], accg, 0, 0, 0);
            accx = __builtin_amdgcn_mfma_f32_16x16x32_bf16(afx[ks], wz[ks], accx, 0, 0, 0);
        }
        #pragma unroll
        for (int r = 0; r < 4; ++r) {
            const size_t p = p0 + t * 16 + q * 4 + r;
            out[p * CC + o] = accx[r] * sigm(accg[r]);
        }
    }
}

// ---------------------------------------------------------------------------
// K3 (legacy fallback, used only if workspace too small for zn handoff).
// ---------------------------------------------------------------------------
__global__ __launch_bounds__(256) void k3_out(
    float* __restrict__ out, const u16* __restrict__ x_cm,
    const float* __restrict__ z,
    const float* __restrict__ wi, const float* __restrict__ bi,
    const float* __restrict__ wo, const float* __restrict__ bo,
    const u16* __restrict__ wpk,
    const float* __restrict__ gbv, const float* __restrict__ zbv)
{
    __shared__ u16 A[128][136];
    __shared__ u16 Bt[128][136];
    const int tid = threadIdx.x;
    const size_t p0 = (size_t)blockIdx.x * 128;
    const int wave = tid >> 6, lane = tid & 63;
    const int m = lane & 15, q = lane >> 4;
    const int pl = tid >> 1, ht = tid & 1;

    {
        const float* zr = z + (p0 + pl) * CC + ht * 64;
        float v[64];
        #pragma unroll
        for (int h = 0; h < 16; ++h) {
            f32x4 t = *(const f32x4*)(zr + h * 4);
            #pragma unroll
            for (int e = 0; e < 4; ++e) v[h * 4 + e] = t[e];
        }
        float s = 0.f, s2 = 0.f;
        #pragma unroll
        for (int e = 0; e < 64; ++e) { s += v[e]; s2 += v[e] * v[e]; }
        s  += __shfl_xor(s, 1);
        s2 += __shfl_xor(s2, 1);
        const float mu   = s * (1.0f / CC);
        const float rstd = rsqrtf(s2 * (1.0f / CC) - mu * mu + 1e-5f);
        #pragma unroll
        for (int h = 0; h < 8; ++h) {
            u16x8 o8;
            #pragma unroll
            for (int e = 0; e < 8; ++e) {
                const int c = ht * 64 + h * 8 + e;
                o8[e] = f2b((v[h * 8 + e] - mu) * rstd * wi[c] + bi[c]);
            }
            *(u16x8*)&A[pl][ht * 64 + h * 8] = o8;
        }
    }
    {
        const int c = tid >> 1, seg = tid & 1;
        #pragma unroll
        for (int e = 0; e < 8; ++e) {
            u16x8 vv = *(const u16x8*)(x_cm + (size_t)c * CPITCH + p0 + seg * 64 + e * 8);
            *(u16x8*)&Bt[c][seg * 64 + e * 8] = vv;
        }
    }
    __syncthreads();

    bf16x8 afz[2][4];
    #pragma unroll
    for (int t = 0; t < 2; ++t)
        #pragma unroll
        for (int ks = 0; ks < 4; ++ks)
            afz[t][ks] = *(const bf16x8*)&A[wave * 32 + t * 16 + m][ks * 32 + q * 8];
    __syncthreads();

    {
        float v[64];
        #pragma unroll
        for (int e = 0; e < 64; ++e) v[e] = b2f(Bt[ht * 64 + e][pl]);
        float s = 0.f, s2 = 0.f;
        #pragma unroll
        for (int e = 0; e < 64; ++e) { s += v[e]; s2 += v[e] * v[e]; }
        s  += __shfl_xor(s, 1);
        s2 += __shfl_xor(s2, 1);
        const float mu   = s * (1.0f / CC);
        const float rstd = rsqrtf(s2 * (1.0f / CC) - mu * mu + 1e-5f);
        #pragma unroll
        for (int h = 0; h < 8; ++h) {
            u16x8 o8;
            #pragma unroll
            for (int e = 0; e < 8; ++e) {
                const int c = ht * 64 + h * 8 + e;
                o8[e] = f2b((v[h * 8 + e] - mu) * rstd * wo[c] + bo[c]);
            }
            *(u16x8*)&A[pl][ht * 64 + h * 8] = o8;
        }
    }
    __syncthreads();

    bf16x8 afx[2][4];
    #pragma unroll
    for (int t = 0; t < 2; ++t)
        #pragma unroll
        for (int ks = 0; ks < 4; ++ks)
            afx[t][ks] = *(const bf16x8*)&A[wave * 32 + t * 16 + m][ks * 32 + q * 8];

    for (int cb = 0; cb < 8; ++cb) {
        const int o = cb * 16 + m;
        const float gb0 = gbv[o], zb0 = zbv[o];
        f32x4 accg[2], accx[2];
        #pragma unroll
        for (int t = 0; t < 2; ++t) {
            accg[t] = f32x4{ gb0, gb0, gb0, gb0 };
            accx[t] = f32x4{ zb0, zb0, zb0, zb0 };
        }
        const u16* wpg = wpk + ((size_t)((4 * 8 + cb) * 4)) * 512 + (size_t)lane * 8;
        const u16* wpz = wpk + ((size_t)((5 * 8 + cb) * 4)) * 512 + (size_t)lane * 8;
        bf16x8 wg[4], wz[4];
        #pragma unroll
        for (int ks = 0; ks < 4; ++ks) {
            wg[ks] = *(const bf16x8*)(wpg + ks * 512);
            wz[ks] = *(const bf16x8*)(wpz + ks * 512);
        }
        #pragma unroll
        for (int ks = 0; ks < 4; ++ks)
            #pragma unroll
            for (int t = 0; t < 2; ++t) {
                accg[t] = __builtin_amdgcn_mfma_f32_16x16x32_bf16(
                            afz[t][ks], wg[ks], accg[t], 0, 0, 0);
                accx[t] = __builtin_amdgcn_mfma_f32_16x16x32_bf16(
                            afx[t][ks], wz[ks], accx[t], 0, 0, 0);
            }
        #pragma unroll
        for (int t = 0; t < 2; ++t)
            #pragma unroll
            for (int r = 0; r < 4; ++r) {
                const size_t p = p0 + wave * 32 + t * 16 + q * 4 + r;
                out[p * CC + o] = accx[t][r] * sigm(accg[t][r]);
            }
    }
}

// ---------------------------------------------------------------------------
extern "C" void kernel_launch(void* const* d_in, const int* in_sizes, int n_in,
                              void* d_out, int out_size, void* d_ws, size_t ws_size,
                              hipStream_t stream)
{
    const float* z    = (const float*)d_in[0];
    const float* mask = (const float*)d_in[1];
    const float* wi   = (const float*)d_in[2];
    const float* bi   = (const float*)d_in[3];
    const float* apw  = (const float*)d_in[4];
    const float* apb  = (const float*)d_in[5];
    const float* agw  = (const float*)d_in[6];
    const float* agb  = (const float*)d_in[7];
    const float* bpw  = (const float*)d_in[8];
    const float* bpb  = (const float*)d_in[9];
    const float* bgw  = (const float*)d_in[10];
    const float* bgb  = (const float*)d_in[11];
    const float* gw   = (const float*)d_in[12];
    const float* gb   = (const float*)d_in[13];
    const float* zw   = (const float*)d_in[14];
    const float* zb   = (const float*)d_in[15];
    const float* wo   = (const float*)d_in[16];
    const float* bo   = (const float*)d_in[17];

    u16* a_cm = (u16*)d_ws;                          // [c][CPITCH] bf16
    u16* b_cm = a_cm + (size_t)CC * CPITCH;
    u16* x_cm = b_cm + (size_t)CC * CPITCH;
    u16* w_pk = x_cm + (size_t)CC * CPITCH;          // 192 KiB packed frags
    u16* zn_pm = w_pk + (size_t)6 * 16384;           // 64 MiB zn handoff
    float* out = (float*)d_out;

    const size_t need_zn =
        ((size_t)CC * CPITCH * 3 + 6 * 16384 + (size_t)NPOS * CC) * sizeof(u16);
    const bool use_zn = (ws_size == 0) || (ws_size >= need_zn);
    if (!use_zn) zn_pm = nullptr;

    W6 w6; w6.p[0] = agw; w6.p[1] = apw; w6.p[2] = bgw; w6.p[3] = bpw;
    w6.p[4] = gw; w6.p[5] = zw;

    k0_pack<<<6 * 16384 / 256, 256, 0, stream>>>(w6, w_pk);
    k1_ln_proj<<<NPOS / 128, 512, 0, stream>>>(z, mask, wi, bi, w_pk,
                                               agb, apb, bgb, bpb, a_cm, b_cm, zn_pm);
    k2_gemm<<<128 * 16, 256, 0, stream>>>(a_cm, b_cm, x_cm);
    if (use_zn)
        k3_out_v3<<<NPOS / 128, 512, 0, stream>>>(out, x_cm, zn_pm, wo, bo,
                                                  w_pk, gb, zb);
    else
        k3_out<<<NPOS / 128, 256, 0, stream>>>(out, x_cm, z, wi, bi, wo, bo,
                                               w_pk, gb, zb);
}